// Round 3
// baseline (581.026 us; speedup 1.0000x reference)
//
#include <hip/hip_runtime.h>

#define T_TOK 2048
#define TOPK  8
#define NEXP  32
#define HDIM  1024
#define IDIM  768
#define NPAIR (T_TOK * TOPK)   // 16384
#define BM 128
#define BK 32
#define MT_MAX (NPAIR / BM + NEXP)  // 160 upper bound on sum(ceil(Me/BM))

typedef __attribute__((ext_vector_type(8))) short short8;   // 8 x bf16 (4 VGPRs)
typedef __attribute__((ext_vector_type(4))) float f32x4;    // MFMA accumulator

__device__ __forceinline__ unsigned short f2bf(float f) {
    unsigned x = __float_as_uint(f);
    unsigned r = x + 0x7fffu + ((x >> 16) & 1u);
    return (unsigned short)(r >> 16);
}
__device__ __forceinline__ float bf2f(unsigned short u) {
    return __uint_as_float(((unsigned)u) << 16);
}

// async global->LDS DMA, 16B per lane; LDS dest = wave-uniform base + lane*16
__device__ __forceinline__ void gl_lds16(const unsigned short* g, void* l) {
    __builtin_amdgcn_global_load_lds((const __attribute__((address_space(1))) void*)g,
                                     (__attribute__((address_space(3))) void*)l, 16, 0, 0);
}

// ---------------- fp32 -> bf16 convert ----------------
__global__ void k_conv(const float* __restrict__ src, unsigned short* __restrict__ dst, int n4) {
    int i = blockIdx.x * 256 + threadIdx.x;
    if (i < n4) {
        float4 v = ((const float4*)src)[i];
        ushort4 o;
        o.x = f2bf(v.x); o.y = f2bf(v.y); o.z = f2bf(v.z); o.w = f2bf(v.w);
        ((ushort4*)dst)[i] = o;
    }
}

// ---------------- routing kernels ----------------
__global__ void k_init(int* counts) {
    if (threadIdx.x < NEXP) counts[threadIdx.x] = 0;
}

__global__ void k_hist(const int* __restrict__ idx, int* __restrict__ counts) {
    int p = blockIdx.x * 256 + threadIdx.x;
    atomicAdd(&counts[idx[p]], 1);
}

__global__ void k_scan(const int* __restrict__ counts, int* __restrict__ offsets,
                       int* __restrict__ mtb, int* __restrict__ cursor) {
    if (threadIdx.x == 0) {
        int tot = 0, mt = 0;
        for (int e = 0; e < NEXP; ++e) {
            offsets[e] = tot; mtb[e] = mt;
            tot += counts[e];
            mt += (counts[e] + BM - 1) / BM;
        }
        offsets[NEXP] = tot; mtb[NEXP] = mt;
    }
    if (threadIdx.x < NEXP) cursor[threadIdx.x] = 0;
}

__global__ void k_scatter(const int* __restrict__ idx, int* __restrict__ cursor,
                          const int* __restrict__ offsets, int* __restrict__ pair_token,
                          int* __restrict__ pair_slot) {
    int p = blockIdx.x * 256 + threadIdx.x;
    int e = idx[p];
    int pos = atomicAdd(&cursor[e], 1);
    int slot = offsets[e] + pos;
    pair_token[slot] = p >> 3;   // p / TOPK
    pair_slot[p] = slot;
}

// ---------------- gate+up fused GEMM + SwiGLU (m97-style async staging) ----------------
// A: 128 x 32 bf16 (gathered token rows), Bg/Bu: 64 x 32 bf16.
// LDS chunk order == fragment order: chunk c -> row m=((c>>6)<<4)|(c&15), kq=(c>>4)&3.
__global__ __launch_bounds__(256) void k_gateup(
    const unsigned short* __restrict__ hid_bf, const unsigned short* __restrict__ gate_bf,
    const unsigned short* __restrict__ up_bf, const int* __restrict__ pair_token,
    const int* __restrict__ offsets, const int* __restrict__ mtb,
    unsigned short* __restrict__ h_mid)
{
    __shared__ short8 sA[512], sBg[256], sBu[256];
    __shared__ int sInfo[4];
    int tid = threadIdx.x;
    if (tid == 0) {
        int mt = blockIdx.x;
        if (mt >= mtb[NEXP]) { sInfo[0] = -1; }
        else {
            int e = 0;
            while (mtb[e + 1] <= mt) e++;
            sInfo[0] = e; sInfo[1] = offsets[e];
            sInfo[2] = offsets[e + 1] - offsets[e];
            sInfo[3] = (mt - mtb[e]) * BM;
        }
    }
    __syncthreads();
    int e = sInfo[0];
    if (e < 0) return;
    int off = sInfo[1], Me = sInfo[2], mrow0 = sInfo[3];
    int n0 = blockIdx.y * 64;

    int wave = tid >> 6, lane = tid & 63, quad = lane >> 4, l16 = lane & 15;

    // ---- staging addresses (per lane, fixed rows; advance by k0 each iter) ----
    // A: lane covers rows m0 = wave*32 + l16 and m1 = m0 + 16, k-offset quad*8
    int m0 = wave * 32 + l16, m1 = m0 + 16;
    int rp0 = mrow0 + m0, rp1 = mrow0 + m1;
    int tok0 = (rp0 < Me) ? pair_token[off + rp0] : 0;
    int tok1 = (rp1 < Me) ? pair_token[off + rp1] : 0;
    const unsigned short* aG0 = hid_bf + (size_t)tok0 * HDIM + quad * 8;
    const unsigned short* aG1 = hid_bf + (size_t)tok1 * HDIM + quad * 8;
    // B: lane covers row n = wave*16 + l16, k-offset quad*8
    int nB = n0 + wave * 16 + l16;
    const unsigned short* gG = gate_bf + ((size_t)e * IDIM + nB) * HDIM + quad * 8;
    const unsigned short* uG = up_bf   + ((size_t)e * IDIM + nB) * HDIM + quad * 8;
    void* ldsA0 = (void*)&sA[wave * 128];
    void* ldsA1 = (void*)&sA[wave * 128 + 64];
    void* ldsBg = (void*)&sBg[wave * 64];
    void* ldsBu = (void*)&sBu[wave * 64];

    // ---- compute mapping: wave tile 64(m) x 32(n), frags 4(m) x 2(n) ----
    int wm = (wave & 1) * 64, wn = (wave >> 1) * 32;
    int aBase = (wm >> 4) * 64 + quad * 16 + l16;
    int bBase = (wn >> 4) * 64 + quad * 16 + l16;

    f32x4 zero = {0.f, 0.f, 0.f, 0.f};
    f32x4 accg[4][2], accu[4][2];
#pragma unroll
    for (int i = 0; i < 4; ++i)
#pragma unroll
        for (int j = 0; j < 2; ++j) { accg[i][j] = zero; accu[i][j] = zero; }

    for (int k0 = 0; k0 < HDIM; k0 += BK) {
        gl_lds16(aG0 + k0, ldsA0);
        gl_lds16(aG1 + k0, ldsA1);
        gl_lds16(gG + k0, ldsBg);
        gl_lds16(uG + k0, ldsBu);
        __syncthreads();
        short8 af[4];
#pragma unroll
        for (int fm = 0; fm < 4; ++fm) af[fm] = sA[aBase + fm * 64];
#pragma unroll
        for (int fn = 0; fn < 2; ++fn) {
            short8 bg = sBg[bBase + fn * 64];
            short8 bu = sBu[bBase + fn * 64];
#pragma unroll
            for (int fm = 0; fm < 4; ++fm) {
                accg[fm][fn] = __builtin_amdgcn_mfma_f32_16x16x32_bf16(af[fm], bg, accg[fm][fn], 0, 0, 0);
                accu[fm][fn] = __builtin_amdgcn_mfma_f32_16x16x32_bf16(af[fm], bu, accu[fm][fn], 0, 0, 0);
            }
        }
        __syncthreads();
    }

    // epilogue: silu(g)*u -> bf16 h_mid   (C/D: row=(lane>>4)*4+reg, col=lane&15)
#pragma unroll
    for (int fm = 0; fm < 4; ++fm)
#pragma unroll
        for (int fn = 0; fn < 2; ++fn)
#pragma unroll
            for (int r = 0; r < 4; ++r) {
                int mloc = wm + fm * 16 + quad * 4 + r;
                int prow = mrow0 + mloc;
                if (prow < Me) {
                    int col = n0 + wn + fn * 16 + l16;
                    float g = accg[fm][fn][r], u = accu[fm][fn][r];
                    float h = g / (1.f + __expf(-g)) * u;
                    h_mid[(size_t)(off + prow) * IDIM + col] = f2bf(h);
                }
            }
}

// ---------------- down GEMM (m97-style async staging) ----------------
// A: 128 x 32 bf16 from h_mid, B: 128 x 32 bf16 from down_bf.
__global__ __launch_bounds__(256) void k_down(
    const unsigned short* __restrict__ h_mid, const unsigned short* __restrict__ down_bf,
    const int* __restrict__ offsets, const int* __restrict__ mtb,
    unsigned short* __restrict__ y_pair)
{
    __shared__ short8 sA[512], sB[512];
    __shared__ int sInfo[4];
    int tid = threadIdx.x;
    if (tid == 0) {
        int mt = blockIdx.x;
        if (mt >= mtb[NEXP]) { sInfo[0] = -1; }
        else {
            int e = 0;
            while (mtb[e + 1] <= mt) e++;
            sInfo[0] = e; sInfo[1] = offsets[e];
            sInfo[2] = offsets[e + 1] - offsets[e];
            sInfo[3] = (mt - mtb[e]) * BM;
        }
    }
    __syncthreads();
    int e = sInfo[0];
    if (e < 0) return;
    int off = sInfo[1], Me = sInfo[2], mrow0 = sInfo[3];
    int n0 = blockIdx.y * 128;

    int wave = tid >> 6, lane = tid & 63, quad = lane >> 4, l16 = lane & 15;

    // A staging: rows m0 = wave*32+l16, m1 = m0+16
    int m0 = wave * 32 + l16, m1 = m0 + 16;
    int rp0 = mrow0 + m0; if (rp0 >= Me) rp0 = 0;
    int rp1 = mrow0 + m1; if (rp1 >= Me) rp1 = 0;
    const unsigned short* aG0 = h_mid + (size_t)(off + rp0) * IDIM + quad * 8;
    const unsigned short* aG1 = h_mid + (size_t)(off + rp1) * IDIM + quad * 8;
    // B staging: rows nb0 = wave*32+l16, nb1 = nb0+16
    int nb0 = n0 + wave * 32 + l16, nb1 = nb0 + 16;
    const unsigned short* bG0 = down_bf + ((size_t)e * HDIM + nb0) * IDIM + quad * 8;
    const unsigned short* bG1 = down_bf + ((size_t)e * HDIM + nb1) * IDIM + quad * 8;
    void* ldsA0 = (void*)&sA[wave * 128];
    void* ldsA1 = (void*)&sA[wave * 128 + 64];
    void* ldsB0 = (void*)&sB[wave * 128];
    void* ldsB1 = (void*)&sB[wave * 128 + 64];

    int wm = (wave & 1) * 64, wn = (wave >> 1) * 64;
    int aBase = (wm >> 4) * 64 + quad * 16 + l16;
    int bBase = (wn >> 4) * 64 + quad * 16 + l16;

    f32x4 zero = {0.f, 0.f, 0.f, 0.f};
    f32x4 acc[4][4];
#pragma unroll
    for (int i = 0; i < 4; ++i)
#pragma unroll
        for (int j = 0; j < 4; ++j) acc[i][j] = zero;

    for (int k0 = 0; k0 < IDIM; k0 += BK) {
        gl_lds16(aG0 + k0, ldsA0);
        gl_lds16(aG1 + k0, ldsA1);
        gl_lds16(bG0 + k0, ldsB0);
        gl_lds16(bG1 + k0, ldsB1);
        __syncthreads();
        short8 af[4];
#pragma unroll
        for (int fm = 0; fm < 4; ++fm) af[fm] = sA[aBase + fm * 64];
#pragma unroll
        for (int fn = 0; fn < 4; ++fn) {
            short8 bf = sB[bBase + fn * 64];
#pragma unroll
            for (int fm = 0; fm < 4; ++fm)
                acc[fm][fn] = __builtin_amdgcn_mfma_f32_16x16x32_bf16(af[fm], bf, acc[fm][fn], 0, 0, 0);
        }
        __syncthreads();
    }

#pragma unroll
    for (int fm = 0; fm < 4; ++fm)
#pragma unroll
        for (int fn = 0; fn < 4; ++fn)
#pragma unroll
            for (int r = 0; r < 4; ++r) {
                int mloc = wm + fm * 16 + quad * 4 + r;
                int prow = mrow0 + mloc;
                if (prow < Me) {
                    int col = n0 + wn + fn * 16 + l16;
                    y_pair[(size_t)(off + prow) * HDIM + col] = f2bf(acc[fm][fn][r]);
                }
            }
}

// ---------------- per-token weighted reduce ----------------
__global__ void k_reduce(const unsigned short* __restrict__ y_pair,
                         const int* __restrict__ pair_slot,
                         const float* __restrict__ topw, float* __restrict__ out)
{
    int t = blockIdx.x;
    __shared__ int ss[TOPK];
    __shared__ float sw[TOPK];
    if (threadIdx.x < TOPK) {
        ss[threadIdx.x] = pair_slot[t * TOPK + threadIdx.x];
        sw[threadIdx.x] = topw[t * TOPK + threadIdx.x];
    }
    __syncthreads();
    int c = threadIdx.x * 4;
    float a0 = 0.f, a1 = 0.f, a2 = 0.f, a3 = 0.f;
    for (int k = 0; k < TOPK; ++k) {
        const unsigned short* yr = y_pair + (size_t)ss[k] * HDIM + c;
        uint2 v = *(const uint2*)yr;
        float w = sw[k];
        a0 += w * bf2f((unsigned short)(v.x & 0xffff));
        a1 += w * bf2f((unsigned short)(v.x >> 16));
        a2 += w * bf2f((unsigned short)(v.y & 0xffff));
        a3 += w * bf2f((unsigned short)(v.y >> 16));
    }
    float4 o = {a0, a1, a2, a3};
    *(float4*)(out + (size_t)t * HDIM + c) = o;
}

extern "C" void kernel_launch(void* const* d_in, const int* in_sizes, int n_in,
                              void* d_out, int out_size, void* d_ws, size_t ws_size,
                              hipStream_t stream) {
    (void)in_sizes; (void)n_in; (void)out_size; (void)ws_size;
    const float* hidden = (const float*)d_in[0];
    const int*   tki    = (const int*)d_in[1];
    const float* tkw    = (const float*)d_in[2];
    const float* gate   = (const float*)d_in[3];
    const float* up     = (const float*)d_in[4];
    const float* down   = (const float*)d_in[5];
    float* out = (float*)d_out;

    // ws layout (131 MB):
    //   [0]            h_mid   25,165,824 B  (live: gateup -> down)
    //   [25,165,824]   hid_bf   4,194,304 B  (live: conv -> gateup)
    //   [29,360,128]   region1 50,331,648 B  gate_bf; later down_bf (after gateup)
    //   [79,691,776]   region2 50,331,648 B  up_bf;   later y_pair  (after gateup)
    //   [130,023,424]  int scratch
    char* w = (char*)d_ws;
    unsigned short* h_mid   = (unsigned short*)w;
    unsigned short* hid_bf  = (unsigned short*)(w + 25165824);
    unsigned short* gate_bf = (unsigned short*)(w + 29360128);
    unsigned short* up_bf   = (unsigned short*)(w + 79691776);
    unsigned short* down_bf = gate_bf;   // aliases gate_bf after k_gateup completes
    unsigned short* y_pair  = up_bf;     // aliases up_bf   after k_gateup completes
    int* ib = (int*)(w + 130023424);
    int* pair_token = ib;                // NPAIR
    int* pair_slot  = ib + NPAIR;        // NPAIR
    int* counts     = ib + 2 * NPAIR;    // NEXP
    int* cursor     = counts + NEXP;     // NEXP
    int* offsets    = cursor + NEXP;     // NEXP+1
    int* mtb        = offsets + NEXP + 1;// NEXP+1

    const int W4 = NEXP * IDIM * HDIM / 4;   // 6,291,456 float4 per weight tensor
    const int H4 = T_TOK * HDIM / 4;         // 524,288

    k_init<<<1, 64, 0, stream>>>(counts);
    k_hist<<<NPAIR / 256, 256, 0, stream>>>(tki, counts);
    k_scan<<<1, 64, 0, stream>>>(counts, offsets, mtb, cursor);
    k_scatter<<<NPAIR / 256, 256, 0, stream>>>(tki, cursor, offsets, pair_token, pair_slot);

    k_conv<<<(H4 + 255) / 256, 256, 0, stream>>>(hidden, hid_bf, H4);
    k_conv<<<(W4 + 255) / 256, 256, 0, stream>>>(gate, gate_bf, W4);
    k_conv<<<(W4 + 255) / 256, 256, 0, stream>>>(up, up_bf, W4);

    k_gateup<<<dim3(MT_MAX, IDIM / 64), 256, 0, stream>>>(hid_bf, gate_bf, up_bf,
                                                          pair_token, offsets, mtb, h_mid);

    k_conv<<<(W4 + 255) / 256, 256, 0, stream>>>(down, down_bf, W4);

    k_down<<<dim3(MT_MAX, HDIM / 128), 256, 0, stream>>>(h_mid, down_bf, offsets, mtb, y_pair);
    k_reduce<<<T_TOK, 256, 0, stream>>>(y_pair, pair_slot, tkw, out);
}

// Round 4
// 558.824 us; speedup vs baseline: 1.0397x; 1.0397x over previous
//
#include <hip/hip_runtime.h>

#define T_TOK 2048
#define TOPK  8
#define NEXP  32
#define HDIM  1024
#define IDIM  768
#define NPAIR (T_TOK * TOPK)   // 16384
#define BM 128
#define BK 32
#define MT_MAX (NPAIR / BM + NEXP)  // 160 upper bound on sum(ceil(Me/BM))

typedef __attribute__((ext_vector_type(8))) short short8;   // 8 x bf16 (4 VGPRs)
typedef __attribute__((ext_vector_type(4))) float f32x4;    // MFMA accumulator

__device__ __forceinline__ unsigned short f2bf(float f) {
    unsigned x = __float_as_uint(f);
    unsigned r = x + 0x7fffu + ((x >> 16) & 1u);
    return (unsigned short)(r >> 16);
}
__device__ __forceinline__ float bf2f(unsigned short u) {
    return __uint_as_float(((unsigned)u) << 16);
}

// async global->LDS DMA, 16B per lane; LDS dest = wave-uniform base + lane*16
__device__ __forceinline__ void gl_lds16(const unsigned short* g, void* l) {
    __builtin_amdgcn_global_load_lds((const __attribute__((address_space(1))) void*)g,
                                     (__attribute__((address_space(3))) void*)l, 16, 0, 0);
}

// ---------------- fp32 -> bf16 convert (two tensors, contiguous dst) ----------------
__global__ void k_conv2(const float* __restrict__ src0, const float* __restrict__ src1,
                        unsigned short* __restrict__ dst, int n4each) {
    int i = blockIdx.x * 256 + threadIdx.x;
    const float* s = (i < n4each) ? src0 : src1;
    int j = (i < n4each) ? i : i - n4each;
    if (i < 2 * n4each) {
        float4 v = ((const float4*)s)[j];
        ushort4 o;
        o.x = f2bf(v.x); o.y = f2bf(v.y); o.z = f2bf(v.z); o.w = f2bf(v.w);
        ((ushort4*)dst)[i] = o;
    }
}

__global__ void k_conv(const float* __restrict__ src, unsigned short* __restrict__ dst, int n4) {
    int i = blockIdx.x * 256 + threadIdx.x;
    if (i < n4) {
        float4 v = ((const float4*)src)[i];
        ushort4 o;
        o.x = f2bf(v.x); o.y = f2bf(v.y); o.z = f2bf(v.z); o.w = f2bf(v.w);
        ((ushort4*)dst)[i] = o;
    }
}

// ---------------- routing kernels ----------------
__global__ void k_init(int* counts) {
    if (threadIdx.x < NEXP) counts[threadIdx.x] = 0;
}

__global__ void k_hist(const int* __restrict__ idx, int* __restrict__ counts) {
    int p = blockIdx.x * 256 + threadIdx.x;
    atomicAdd(&counts[idx[p]], 1);
}

__global__ void k_scan(const int* __restrict__ counts, int* __restrict__ offsets,
                       int* __restrict__ mtb, int* __restrict__ cursor) {
    if (threadIdx.x == 0) {
        int tot = 0, mt = 0;
        for (int e = 0; e < NEXP; ++e) {
            offsets[e] = tot; mtb[e] = mt;
            tot += counts[e];
            mt += (counts[e] + BM - 1) / BM;
        }
        offsets[NEXP] = tot; mtb[NEXP] = mt;
    }
    if (threadIdx.x < NEXP) cursor[threadIdx.x] = 0;
}

__global__ void k_scatter(const int* __restrict__ idx, int* __restrict__ cursor,
                          const int* __restrict__ offsets, int* __restrict__ pair_token,
                          int* __restrict__ pair_slot) {
    int p = blockIdx.x * 256 + threadIdx.x;
    int e = idx[p];
    int pos = atomicAdd(&cursor[e], 1);
    int slot = offsets[e] + pos;
    pair_token[slot] = p >> 3;   // p / TOPK
    pair_slot[p] = slot;
}

// ---------------- gate+up fused GEMM + SwiGLU ----------------
// BM=128, BN=128, BK=32. Per wave per K-iter: 32 MFMA. acc = 128 VGPRs.
// LDS chunk c (16B) -> row m = ((c>>6)<<4)|(c&15), kq = (c>>4)&3.
__global__ __launch_bounds__(256, 2) void k_gateup(
    const unsigned short* __restrict__ hid_bf, const unsigned short* __restrict__ gate_bf,
    const unsigned short* __restrict__ up_bf, const int* __restrict__ pair_token,
    const int* __restrict__ offsets, const int* __restrict__ mtb,
    unsigned short* __restrict__ h_mid)
{
    __shared__ short8 sA[512], sBg[512], sBu[512];
    __shared__ int sInfo[4];
    int tid = threadIdx.x;
    if (tid == 0) {
        int mt = blockIdx.x;
        if (mt >= mtb[NEXP]) { sInfo[0] = -1; }
        else {
            int e = 0;
            while (mtb[e + 1] <= mt) e++;
            sInfo[0] = e; sInfo[1] = offsets[e];
            sInfo[2] = offsets[e + 1] - offsets[e];
            sInfo[3] = (mt - mtb[e]) * BM;
        }
    }
    __syncthreads();
    int e = sInfo[0];
    if (e < 0) return;
    int off = sInfo[1], Me = sInfo[2], mrow0 = sInfo[3];
    int n0 = blockIdx.y * 128;

    int wave = tid >> 6, lane = tid & 63, quad = lane >> 4, l16 = lane & 15;

    // ---- staging: wave w covers rows w*32+l16 and w*32+16+l16 of each 128-row tile
    int m0 = wave * 32 + l16, m1 = m0 + 16;
    int rp0 = mrow0 + m0, rp1 = mrow0 + m1;
    int tok0 = (rp0 < Me) ? pair_token[off + rp0] : 0;
    int tok1 = (rp1 < Me) ? pair_token[off + rp1] : 0;
    const unsigned short* aG0 = hid_bf + (size_t)tok0 * HDIM + quad * 8;
    const unsigned short* aG1 = hid_bf + (size_t)tok1 * HDIM + quad * 8;
    const unsigned short* gG0 = gate_bf + ((size_t)e * IDIM + n0 + m0) * HDIM + quad * 8;
    const unsigned short* gG1 = gate_bf + ((size_t)e * IDIM + n0 + m1) * HDIM + quad * 8;
    const unsigned short* uG0 = up_bf + ((size_t)e * IDIM + n0 + m0) * HDIM + quad * 8;
    const unsigned short* uG1 = up_bf + ((size_t)e * IDIM + n0 + m1) * HDIM + quad * 8;
    void* ldsA0 = (void*)&sA[wave * 128];  void* ldsA1 = (void*)&sA[wave * 128 + 64];
    void* ldsG0 = (void*)&sBg[wave * 128]; void* ldsG1 = (void*)&sBg[wave * 128 + 64];
    void* ldsU0 = (void*)&sBu[wave * 128]; void* ldsU1 = (void*)&sBu[wave * 128 + 64];

    // ---- compute: 2x2 waves, wave tile 64x64, frags 4x4 per tensor
    int wm = (wave & 1) * 64, wn = (wave >> 1) * 64;
    int aBase = (wm >> 4) * 64 + quad * 16 + l16;
    int bBase = (wn >> 4) * 64 + quad * 16 + l16;

    f32x4 zero = {0.f, 0.f, 0.f, 0.f};
    f32x4 accg[4][4], accu[4][4];
#pragma unroll
    for (int i = 0; i < 4; ++i)
#pragma unroll
        for (int j = 0; j < 4; ++j) { accg[i][j] = zero; accu[i][j] = zero; }

    for (int k0 = 0; k0 < HDIM; k0 += BK) {
        gl_lds16(aG0 + k0, ldsA0); gl_lds16(aG1 + k0, ldsA1);
        gl_lds16(gG0 + k0, ldsG0); gl_lds16(gG1 + k0, ldsG1);
        gl_lds16(uG0 + k0, ldsU0); gl_lds16(uG1 + k0, ldsU1);
        __syncthreads();
        short8 af[4];
#pragma unroll
        for (int fm = 0; fm < 4; ++fm) af[fm] = sA[aBase + fm * 64];
#pragma unroll
        for (int fn = 0; fn < 4; ++fn) {
            short8 bg = sBg[bBase + fn * 64];
            short8 bu = sBu[bBase + fn * 64];
#pragma unroll
            for (int fm = 0; fm < 4; ++fm) {
                accg[fm][fn] = __builtin_amdgcn_mfma_f32_16x16x32_bf16(af[fm], bg, accg[fm][fn], 0, 0, 0);
                accu[fm][fn] = __builtin_amdgcn_mfma_f32_16x16x32_bf16(af[fm], bu, accu[fm][fn], 0, 0, 0);
            }
        }
        __syncthreads();
    }

    // epilogue: silu(g)*u -> bf16 h_mid   (C/D: row=(lane>>4)*4+reg, col=lane&15)
#pragma unroll
    for (int fm = 0; fm < 4; ++fm)
#pragma unroll
        for (int fn = 0; fn < 4; ++fn)
#pragma unroll
            for (int r = 0; r < 4; ++r) {
                int mloc = wm + fm * 16 + quad * 4 + r;
                int prow = mrow0 + mloc;
                if (prow < Me) {
                    int col = n0 + wn + fn * 16 + l16;
                    float g = accg[fm][fn][r], u = accu[fm][fn][r];
                    float h = g / (1.f + __expf(-g)) * u;
                    h_mid[(size_t)(off + prow) * IDIM + col] = f2bf(h);
                }
            }
}

// ---------------- down GEMM ----------------
// BM=128, BN=256, BK=32. Per wave per K-iter: 32 MFMA. acc = 128 VGPRs.
__global__ __launch_bounds__(256, 2) void k_down(
    const unsigned short* __restrict__ h_mid, const unsigned short* __restrict__ down_bf,
    const int* __restrict__ offsets, const int* __restrict__ mtb,
    unsigned short* __restrict__ y_pair)
{
    __shared__ short8 sA[512], sB[1024];
    __shared__ int sInfo[4];
    int tid = threadIdx.x;
    if (tid == 0) {
        int mt = blockIdx.x;
        if (mt >= mtb[NEXP]) { sInfo[0] = -1; }
        else {
            int e = 0;
            while (mtb[e + 1] <= mt) e++;
            sInfo[0] = e; sInfo[1] = offsets[e];
            sInfo[2] = offsets[e + 1] - offsets[e];
            sInfo[3] = (mt - mtb[e]) * BM;
        }
    }
    __syncthreads();
    int e = sInfo[0];
    if (e < 0) return;
    int off = sInfo[1], Me = sInfo[2], mrow0 = sInfo[3];
    int n0 = blockIdx.y * 256;

    int wave = tid >> 6, lane = tid & 63, quad = lane >> 4, l16 = lane & 15;

    // A staging: rows m0 = wave*32+l16, m1 = m0+16
    int m0 = wave * 32 + l16, m1 = m0 + 16;
    int rp0 = mrow0 + m0; if (rp0 >= Me) rp0 = 0;
    int rp1 = mrow0 + m1; if (rp1 >= Me) rp1 = 0;
    const unsigned short* aG0 = h_mid + (size_t)(off + rp0) * IDIM + quad * 8;
    const unsigned short* aG1 = h_mid + (size_t)(off + rp1) * IDIM + quad * 8;
    // B staging: wave w covers rows n = w*64 + j*16 + l16, j=0..3 (256 rows total)
    const unsigned short* bG0 = down_bf + ((size_t)e * HDIM + n0 + wave * 64 + l16) * IDIM + quad * 8;
    const unsigned short* bG1 = bG0 + (size_t)16 * IDIM;
    const unsigned short* bG2 = bG0 + (size_t)32 * IDIM;
    const unsigned short* bG3 = bG0 + (size_t)48 * IDIM;
    void* ldsA0 = (void*)&sA[wave * 128];      void* ldsA1 = (void*)&sA[wave * 128 + 64];
    void* ldsB0 = (void*)&sB[wave * 256];      void* ldsB1 = (void*)&sB[wave * 256 + 64];
    void* ldsB2 = (void*)&sB[wave * 256 + 128]; void* ldsB3 = (void*)&sB[wave * 256 + 192];

    // compute: 2x2 waves; wave tile 64(m) x 128(n); frags 4(m) x 8(n)
    int wm = (wave & 1) * 64, wn = (wave >> 1) * 128;
    int aBase = (wm >> 4) * 64 + quad * 16 + l16;
    int bBase = (wn >> 4) * 64 + quad * 16 + l16;

    f32x4 zero = {0.f, 0.f, 0.f, 0.f};
    f32x4 acc[4][8];
#pragma unroll
    for (int i = 0; i < 4; ++i)
#pragma unroll
        for (int j = 0; j < 8; ++j) acc[i][j] = zero;

    for (int k0 = 0; k0 < IDIM; k0 += BK) {
        gl_lds16(aG0 + k0, ldsA0); gl_lds16(aG1 + k0, ldsA1);
        gl_lds16(bG0 + k0, ldsB0); gl_lds16(bG1 + k0, ldsB1);
        gl_lds16(bG2 + k0, ldsB2); gl_lds16(bG3 + k0, ldsB3);
        __syncthreads();
        short8 af[4];
#pragma unroll
        for (int fm = 0; fm < 4; ++fm) af[fm] = sA[aBase + fm * 64];
#pragma unroll
        for (int fn = 0; fn < 8; ++fn) {
            short8 bf = sB[bBase + fn * 64];
#pragma unroll
            for (int fm = 0; fm < 4; ++fm)
                acc[fm][fn] = __builtin_amdgcn_mfma_f32_16x16x32_bf16(af[fm], bf, acc[fm][fn], 0, 0, 0);
        }
        __syncthreads();
    }

#pragma unroll
    for (int fm = 0; fm < 4; ++fm)
#pragma unroll
        for (int fn = 0; fn < 8; ++fn)
#pragma unroll
            for (int r = 0; r < 4; ++r) {
                int mloc = wm + fm * 16 + quad * 4 + r;
                int prow = mrow0 + mloc;
                if (prow < Me) {
                    int col = n0 + wn + fn * 16 + l16;
                    y_pair[(size_t)(off + prow) * HDIM + col] = f2bf(acc[fm][fn][r]);
                }
            }
}

// ---------------- per-token weighted reduce ----------------
__global__ void k_reduce(const unsigned short* __restrict__ y_pair,
                         const int* __restrict__ pair_slot,
                         const float* __restrict__ topw, float* __restrict__ out)
{
    int t = blockIdx.x;
    __shared__ int ss[TOPK];
    __shared__ float sw[TOPK];
    if (threadIdx.x < TOPK) {
        ss[threadIdx.x] = pair_slot[t * TOPK + threadIdx.x];
        sw[threadIdx.x] = topw[t * TOPK + threadIdx.x];
    }
    __syncthreads();
    int c = threadIdx.x * 4;
    float a0 = 0.f, a1 = 0.f, a2 = 0.f, a3 = 0.f;
    for (int k = 0; k < TOPK; ++k) {
        const unsigned short* yr = y_pair + (size_t)ss[k] * HDIM + c;
        uint2 v = *(const uint2*)yr;
        float w = sw[k];
        a0 += w * bf2f((unsigned short)(v.x & 0xffff));
        a1 += w * bf2f((unsigned short)(v.x >> 16));
        a2 += w * bf2f((unsigned short)(v.y & 0xffff));
        a3 += w * bf2f((unsigned short)(v.y >> 16));
    }
    float4 o = {a0, a1, a2, a3};
    *(float4*)(out + (size_t)t * HDIM + c) = o;
}

extern "C" void kernel_launch(void* const* d_in, const int* in_sizes, int n_in,
                              void* d_out, int out_size, void* d_ws, size_t ws_size,
                              hipStream_t stream) {
    (void)in_sizes; (void)n_in; (void)out_size; (void)ws_size;
    const float* hidden = (const float*)d_in[0];
    const int*   tki    = (const int*)d_in[1];
    const float* tkw    = (const float*)d_in[2];
    const float* gate   = (const float*)d_in[3];
    const float* up     = (const float*)d_in[4];
    const float* down   = (const float*)d_in[5];
    float* out = (float*)d_out;

    // ws layout (131 MB):
    //   [0]            h_mid   25,165,824 B  (live: gateup -> down)
    //   [25,165,824]   hid_bf   4,194,304 B  (live: conv -> gateup)
    //   [29,360,128]   region1 50,331,648 B  gate_bf; later down_bf (after gateup)
    //   [79,691,776]   region2 50,331,648 B  up_bf;   later y_pair  (after gateup)
    //   [130,023,424]  int scratch
    char* w = (char*)d_ws;
    unsigned short* h_mid   = (unsigned short*)w;
    unsigned short* hid_bf  = (unsigned short*)(w + 25165824);
    unsigned short* gate_bf = (unsigned short*)(w + 29360128);
    unsigned short* up_bf   = (unsigned short*)(w + 79691776);
    unsigned short* down_bf = gate_bf;   // aliases gate_bf after k_gateup completes
    unsigned short* y_pair  = up_bf;     // aliases up_bf   after k_gateup completes
    int* ib = (int*)(w + 130023424);
    int* pair_token = ib;                // NPAIR
    int* pair_slot  = ib + NPAIR;        // NPAIR
    int* counts     = ib + 2 * NPAIR;    // NEXP
    int* cursor     = counts + NEXP;     // NEXP
    int* offsets    = cursor + NEXP;     // NEXP+1
    int* mtb        = offsets + NEXP + 1;// NEXP+1

    const int W4 = NEXP * IDIM * HDIM / 4;   // 6,291,456 float4 per weight tensor
    const int H4 = T_TOK * HDIM / 4;         // 524,288

    k_init<<<1, 64, 0, stream>>>(counts);
    k_hist<<<NPAIR / 256, 256, 0, stream>>>(tki, counts);
    k_scan<<<1, 64, 0, stream>>>(counts, offsets, mtb, cursor);
    k_scatter<<<NPAIR / 256, 256, 0, stream>>>(tki, cursor, offsets, pair_token, pair_slot);

    k_conv<<<(H4 + 255) / 256, 256, 0, stream>>>(hidden, hid_bf, H4);
    k_conv2<<<(2 * W4 + 255) / 256, 256, 0, stream>>>(gate, up, gate_bf, W4);

    k_gateup<<<dim3(MT_MAX, IDIM / 128), 256, 0, stream>>>(hid_bf, gate_bf, up_bf,
                                                           pair_token, offsets, mtb, h_mid);

    k_conv<<<(W4 + 255) / 256, 256, 0, stream>>>(down, down_bf, W4);

    k_down<<<dim3(MT_MAX, HDIM / 256), 256, 0, stream>>>(h_mid, down_bf, offsets, mtb, y_pair);
    k_reduce<<<T_TOK, 256, 0, stream>>>(y_pair, pair_slot, tkw, out);
}